// Round 10
// baseline (396.477 us; speedup 1.0000x reference)
//
#include <hip/hip_runtime.h>

#define D 128
#define BSH 8          // 256 nodes per bucket
#define CAP 12288      // slots per bucket (R17 padding headroom)
#define CH 8192        // edges per k_bin block (512 threads, 391 blocks)
                       // R12 FAILED: per-edge global fp32 atomics ~100us.
                       // R13 WIN: LDS bucket-sort + coalesced copy-out, 428 -> 400us.
                       // R14 WIN: agg8 saddr gathers + prefetch, 400 -> 377us.
                       // R15/R16 FAILED: agg8 grain/depth changes; R14 = local opt.
                       // R17 NEUTRAL: padded CSR; agg8 ~55us structural floor.
                       // R18 WIN: k_bin register edge cache, 377 -> 366us.
                       // R19 REVEALING: exposed wreduce ~61us (all pipes idle).
                       // R20 FAILED (+23): last-block volatile+accumulate loop is a
                       // serialized ~500cy/iter chain; 391-block grid packs 256-CU
                       // machine as 2 waves (2nd half-empty) -> chronic 22% occ.
                       // R21: wreduce decomposed — phase 1 (ow) rides gemm-L1 launch
                       // (hidden); phase 2 = fine-grained streaming kernel (782
                       // blocks, plain vpart stores, no atomics); tiny finalize2.

typedef unsigned short ushort_t;
typedef unsigned int uint_t;
typedef unsigned char uchar_t;

typedef __attribute__((ext_vector_type(8))) short frag_ab;   // 8 bf16 (4 VGPRs)
typedef __attribute__((ext_vector_type(4))) float frag_cd;   // 4 fp32 acc
typedef __attribute__((ext_vector_type(2))) float float2v;

union frag_u { ushort_t u[8]; frag_ab v; };

// Channel permutation: MFMA C-col c = j*16+l16 stored at position p = (c&15)*8 + (c>>4).
// Inverse: c = (p&7)*16 + (p>>3). Elementwise stages use positions; W2 rows and the
// finalize w3 contraction are permuted to match.

__device__ __forceinline__ float bf2f(ushort_t u) {
    union { uint_t i; float f; } v; v.i = ((uint_t)u) << 16; return v.f;
}
__device__ __forceinline__ ushort_t f2bf(float f) {
    union { float f; uint_t i; } v; v.f = f;
    uint_t u = v.i;
    u += 0x7fffu + ((u >> 16) & 1u);   // round-to-nearest-even
    return (ushort_t)(u >> 16);
}

// fp8 accumulate helpers (agg8)
__device__ __forceinline__ void acc_fp8(uint_t w, float2v& aA, float2v& aB) {
    aA += __builtin_amdgcn_cvt_pk_f32_fp8(w, false);
    aB += __builtin_amdgcn_cvt_pk_f32_fp8(w, true);
}
// gather with explicit 32-bit BYTE offset -> saddr+voffset form [R14]
__device__ __forceinline__ uint_t g8(const uint_t* __restrict__ t8, uint_t byteoff) {
    return *(const uint_t*)((const char*)t8 + byteoff);
}

// ---------------- edge binning + weight pack (merged, disjoint block ranges) ------
__launch_bounds__(512)
__global__ void k_binpack(const int* __restrict__ src, const int* __restrict__ dst,
                          int* __restrict__ curA, int* __restrict__ curB,
                          uint_t* __restrict__ binA, uint_t* __restrict__ binB,
                          int E, int nb, int nbin,
                          const float* __restrict__ W1, const float* __restrict__ W2,
                          ushort_t* __restrict__ h1, ushort_t* __restrict__ l1,
                          ushort_t* __restrict__ h2, ushort_t* __restrict__ l2,
                          const float* __restrict__ b1, const float* __restrict__ b2,
                          float* __restrict__ bp1, float* __restrict__ bp2,
                          uint_t* __restrict__ zrow) {
    int tx = threadIdx.x;

    if (blockIdx.x >= nbin) {                      // ---- weight-pack blocks ----
        int wb = blockIdx.x - nbin;
        if (wb == 64) {                            // bias permute + zero row
            if (tx < 128) {
                int c = (tx & 7) * 16 + (tx >> 3);
                bp1[tx] = b1[c];
                bp2[tx] = b2[c];
            }
            if (tx >= 128 && tx < 160) zrow[tx - 128] = 0;
            return;
        }
        int gid = wb * 512 + tx;                   // 0..32767
        int which = gid >> 14;
        int idx = gid & 16383;
        int k = idx >> 7, n = idx & 127;
        float w = which ? W2[(((k & 7) * 16) + (k >> 3)) * 128 + n] : W1[idx];
        ushort_t h = f2bf(w);
        ushort_t l = f2bf(w - bf2f(h));            // residual -> W effectively fp32
        int c = k >> 5, quad = (k >> 3) & 3, jj = k & 7;
        int j = n >> 4, l16 = n & 15;
        int lane = quad * 16 + l16;
        int dest = ((c * 8 + j) * 64 + lane) * 8 + jj;
        if (which) { h2[dest] = h; l2[dest] = l; }
        else       { h1[dest] = h; l1[dest] = l; }
        return;
    }

    // ---- edge-binning blocks (R13 structure + R18 register cache) ----
    __shared__ int hA[512], hB[512], sc[512], gb[512];
    __shared__ ushort_t sbkt[CH];     // bucket id per local slot
    __shared__ uint_t sent[CH];       // packed entry per local slot (bucket-sorted)
    hA[tx] = 0; hB[tx] = 0;
    __syncthreads();

    int e0 = blockIdx.x * CH;
    int e1 = min(e0 + CH, E);
    int total = e1 - e0;

    int sreg[16], dreg[16];
#pragma unroll
    for (int it = 0; it < 16; ++it) {
        int e = e0 + tx + it * 512;
        if (e < e1) {
            int s = src[e], d = dst[e];
            sreg[it] = s; dreg[it] = d;
            atomicAdd(&hA[d >> BSH], 1);
            atomicAdd(&hB[s >> BSH], 1);
        }
    }
    __syncthreads();

    // ================= side A (dst-keyed) =================
    {
        int v = hA[tx];
        sc[tx] = v;
        __syncthreads();
        for (int d = 1; d < 512; d <<= 1) {
            int t = (tx >= d) ? sc[tx - d] : 0;
            __syncthreads();
            sc[tx] += t;
            __syncthreads();
        }
        sc[tx] -= v;                                   // exclusive scan (local base)
        gb[tx] = v ? atomicAdd(&curA[tx], v) : 0;      // global base (bucket-relative)
        hA[tx] = 0;                                    // reuse as local cursor
        __syncthreads();
#pragma unroll
        for (int it = 0; it < 16; ++it) {
            int e = e0 + tx + it * 512;
            if (e < e1) {
                int s = sreg[it], d = dreg[it];
                int k = d >> BSH;
                int pos = sc[k] + atomicAdd(&hA[k], 1);
                sent[pos] = ((uint_t)s << 8) | (uint_t)(d & 255);
                sbkt[pos] = (ushort_t)k;
            }
        }
        __syncthreads();
        for (int p = tx; p < total; p += 512) {        // run-contiguous, coalesced
            int k = sbkt[p];
            int gp = gb[k] + (p - sc[k]);
            if (gp < CAP) binA[(size_t)k * CAP + gp] = sent[p];
        }
        __syncthreads();
    }

    // ================= side B (src-keyed) =================
    {
        int v = hB[tx];
        sc[tx] = v;
        __syncthreads();
        for (int d = 1; d < 512; d <<= 1) {
            int t = (tx >= d) ? sc[tx - d] : 0;
            __syncthreads();
            sc[tx] += t;
            __syncthreads();
        }
        sc[tx] -= v;
        gb[tx] = v ? atomicAdd(&curB[tx], v) : 0;
        hB[tx] = 0;
        __syncthreads();
#pragma unroll
        for (int it = 0; it < 16; ++it) {
            int e = e0 + tx + it * 512;
            if (e < e1) {
                int s = sreg[it], d = dreg[it];
                int k = s >> BSH;
                int pos = sc[k] + atomicAdd(&hB[k], 1);
                sent[pos] = ((uint_t)d << 8) | (uint_t)(s & 255);
                sbkt[pos] = (ushort_t)k;
            }
        }
        __syncthreads();
        for (int p = tx; p < total; p += 512) {
            int k = sbkt[p];
            int gp = gb[k] + (p - sc[k]);
            if (gp < CAP) binB[(size_t)k * CAP + gp] = sent[p];
        }
    }
}

// ---------------- per-bucket: degree + dinv + row ranges + CSR fill + padding ------
__launch_bounds__(1024)
__global__ void k_csr(const uint_t* __restrict__ binA, const int* __restrict__ curA,
                      float* __restrict__ dinv, int* __restrict__ row_beg,
                      int* __restrict__ row_end, int* __restrict__ csr_src, int N) {
    __shared__ int hist[256];
    __shared__ int scan[256];
    __shared__ uint_t ebuf[CAP];      // 48 KB bucket stage (R19)
    int b = blockIdx.x;
    int tx = threadIdx.x;
    int cnt = min(curA[b], CAP);
    const uint_t* eb = binA + (size_t)b * CAP;

    if (tx < 256) hist[tx] = 0;
    __syncthreads();
    for (int e = tx; e < cnt; e += 1024) {
        uint_t pk = eb[e];
        ebuf[e] = pk;
        atomicAdd(&hist[pk & 255u], 1);
    }
    __syncthreads();
    int v = 0, pd = 0;
    if (tx < 256) {
        v = hist[tx];
        pd = (v + 15) & ~15;             // padded segment length
        scan[tx] = pd;
    }
    __syncthreads();
    for (int dd = 1; dd < 256; dd <<= 1) {
        int t = 0;
        if (tx < 256 && tx >= dd) t = scan[tx - dd];
        __syncthreads();
        if (tx < 256) scan[tx] += t;
        __syncthreads();
    }
    if (tx < 256) {
        int my_excl = scan[tx] - pd;
        int node = b * 256 + tx;
        if (node < N) {
            dinv[node] = rsqrtf((float)(v + 1));        // +1 self-loop (actual deg)
            row_beg[node] = b * CAP + my_excl;
            row_end[node] = b * CAP + my_excl + pd;     // padded length
        }
        for (int i = v; i < pd; i++)
            csr_src[b * CAP + my_excl + i] = N;
        hist[tx] = my_excl;                              // reuse as fill cursor
    }
    __syncthreads();
    for (int e = tx; e < cnt; e += 1024) {
        uint_t pk = ebuf[e];
        int pos = b * CAP + atomicAdd(&hist[pk & 255u], 1);
        csr_src[pos] = (int)(pk >> 8);
    }
}

// ---------------- MFMA GEMM + optional ow rider blocks [R21] ----------------------
// blocks [0, gemm_blocks): GEMM with fused scale+fp8 epilogue (unchanged).
// blocks [gemm_blocks, ...): per-bucket ow computation (wreduce phase 1) — LDS
// owacc over binB, coalesced 1KB write to global ow[]. Latency-bound work hides
// under the compute-bound GEMM via CU co-residency.
template <int IN_F32>
__launch_bounds__(256)
__global__ void gemm_mfma(const void* __restrict__ Av, const ushort_t* __restrict__ Whi,
                          const ushort_t* __restrict__ Wlo, const float* __restrict__ dinv,
                          uchar_t* __restrict__ C8, int nrows, int gemm_blocks,
                          const uint_t* __restrict__ binB, const int* __restrict__ curB,
                          float* __restrict__ ow) {
    __shared__ float owacc[256];
    if ((int)blockIdx.x >= gemm_blocks) {          // ---- ow rider block ----
        int b = blockIdx.x - gemm_blocks;
        int tx = threadIdx.x;                      // 256 threads
        owacc[tx] = 0.f;
        __syncthreads();
        int cnt = min(curB[b], CAP);
        const uint_t* eb = binB + (size_t)b * CAP;
        for (int e = tx; e < cnt; e += 256) {
            uint_t pk = eb[e];
            atomicAdd(&owacc[pk & 255u], dinv[pk >> 8]);
        }
        __syncthreads();
        ow[b * 256 + tx] = owacc[tx];
        return;
    }

    int wave = threadIdx.x >> 6;
    int lane = threadIdx.x & 63;
    int quad = lane >> 4, l16 = lane & 15;
    int base = blockIdx.x * 128 + wave * 32;

    frag_cd acc[2][8];
#pragma unroll
    for (int rt = 0; rt < 2; rt++)
#pragma unroll
        for (int j = 0; j < 8; j++) acc[rt][j] = (frag_cd)0.f;

    const ushort_t* Ab = (const ushort_t*)Av;
    const float* Af = (const float*)Av;

#pragma unroll
    for (int c = 0; c < 4; c++) {
        frag_ab afrag[2];
        int koff = c * 32 + quad * 8;
#pragma unroll
        for (int rt = 0; rt < 2; rt++) {
            int row = min(base + rt * 16 + l16, nrows - 1);
            if (IN_F32) {
                const float* ap = Af + (size_t)row * D + koff;
                float4 a0 = *(const float4*)ap;
                float4 a1 = *(const float4*)(ap + 4);
                frag_u fu;
                fu.u[0] = f2bf(a0.x); fu.u[1] = f2bf(a0.y);
                fu.u[2] = f2bf(a0.z); fu.u[3] = f2bf(a0.w);
                fu.u[4] = f2bf(a1.x); fu.u[5] = f2bf(a1.y);
                fu.u[6] = f2bf(a1.z); fu.u[7] = f2bf(a1.w);
                afrag[rt] = fu.v;
            } else {
                afrag[rt] = *(const frag_ab*)(Ab + (size_t)row * D + koff);
            }
        }
#pragma unroll
        for (int j = 0; j < 8; j++) {
            frag_ab bh = *(const frag_ab*)(Whi + (((c * 8 + j) * 64 + lane) * 8));
            frag_ab bl = *(const frag_ab*)(Wlo + (((c * 8 + j) * 64 + lane) * 8));
#pragma unroll
            for (int rt = 0; rt < 2; rt++) {
                acc[rt][j] = __builtin_amdgcn_mfma_f32_16x16x32_bf16(afrag[rt], bh,
                                                                     acc[rt][j], 0, 0, 0);
                acc[rt][j] = __builtin_amdgcn_mfma_f32_16x16x32_bf16(afrag[rt], bl,
                                                                     acc[rt][j], 0, 0, 0);
            }
        }
    }

#pragma unroll
    for (int rt = 0; rt < 2; rt++) {
        int rbase = base + rt * 16 + quad * 4;
#pragma unroll
        for (int reg = 0; reg < 4; reg++) {
            int row = rbase + reg;
            if (row < nrows) {
                float dv = dinv[row];
                uint_t d0 = (uint_t)__builtin_amdgcn_cvt_pk_fp8_f32(
                    acc[rt][0][reg] * dv, acc[rt][1][reg] * dv, 0, false);
                d0 = (uint_t)__builtin_amdgcn_cvt_pk_fp8_f32(
                    acc[rt][2][reg] * dv, acc[rt][3][reg] * dv, (int)d0, true);
                uint_t d1 = (uint_t)__builtin_amdgcn_cvt_pk_fp8_f32(
                    acc[rt][4][reg] * dv, acc[rt][5][reg] * dv, 0, false);
                d1 = (uint_t)__builtin_amdgcn_cvt_pk_fp8_f32(
                    acc[rt][6][reg] * dv, acc[rt][7][reg] * dv, (int)d1, true);
                uint2 o; o.x = d0; o.y = d1;
                *(uint2*)(C8 + (size_t)row * D + l16 * 8) = o;
            }
        }
    }
}

// ---------------- aggregation (pre-scaled fp8 gather, pure sum, bf16 out) ----------
// R14 shape + R17 padded tail-free loop. ~55us structural floor — frozen.
__launch_bounds__(256)
__global__ void agg8(const uint_t* __restrict__ t8, const int* __restrict__ csr_src,
                     const int* __restrict__ row_beg, const int* __restrict__ row_end,
                     const float* __restrict__ dinv, const float* __restrict__ bias,
                     uint_t* __restrict__ out, int n, int do_relu) {
    int node = blockIdx.x * 4 + (threadIdx.x >> 6);
    if (node >= n) return;
    int lane = threadIdx.x & 63;
    int eh = lane >> 5;
    uint_t cl = (uint_t)(lane & 31);
    uint_t cl4 = cl * 4u;

    int beg = row_beg[node];
    int cnt = row_end[node] - beg;     // padded, multiple of 16
    float dn = dinv[node];

    float2v accA = {0.f, 0.f}, accB = {0.f, 0.f};

    if (eh == 0) {   // self term: table already holds dinv[n]*t[n]
        uint_t w = g8(t8, (uint_t)node * 128u + cl4);
        accA = __builtin_amdgcn_cvt_pk_f32_fp8(w, false);
        accB = __builtin_amdgcn_cvt_pk_f32_fp8(w, true);
    }

    int half = cnt >> 1;               // multiple of 8, same for both halves
    int e     = beg + (eh ? half : 0);
    int nfull = half >> 3;             // uniform across the wave

    uint4 sa, sb;
    if (nfull > 0) {
        __builtin_memcpy(&sa, csr_src + e, 16);        // 4B-aligned 16B loads
        __builtin_memcpy(&sb, csr_src + e + 4, 16);
    }
    for (int it = 0; it < nfull; ++it) {
        uint4 ca = sa, cb = sb;
        e += 8;
        if (it + 1 < nfull) {               // prefetch next batch's indices early
            __builtin_memcpy(&sa, csr_src + e, 16);
            __builtin_memcpy(&sb, csr_src + e + 4, 16);
        }
        uint_t w0 = g8(t8, ca.x * 128u + cl4);
        uint_t w1 = g8(t8, ca.y * 128u + cl4);
        uint_t w2 = g8(t8, ca.z * 128u + cl4);
        uint_t w3 = g8(t8, ca.w * 128u + cl4);
        uint_t w4 = g8(t8, cb.x * 128u + cl4);
        uint_t w5 = g8(t8, cb.y * 128u + cl4);
        uint_t w6 = g8(t8, cb.z * 128u + cl4);
        uint_t w7 = g8(t8, cb.w * 128u + cl4);
        acc_fp8(w0, accA, accB);
        acc_fp8(w1, accA, accB);
        acc_fp8(w2, accA, accB);
        acc_fp8(w3, accA, accB);
        acc_fp8(w4, accA, accB);
        acc_fp8(w5, accA, accB);
        acc_fp8(w6, accA, accB);
        acc_fp8(w7, accA, accB);
    }

    float a0 = accA.x, a1 = accA.y, a2 = accB.x, a3 = accB.y;
    a0 += __shfl(a0, lane ^ 32, 64);
    a1 += __shfl(a1, lane ^ 32, 64);
    a2 += __shfl(a2, lane ^ 32, 64);
    a3 += __shfl(a3, lane ^ 32, 64);

    if (eh == 0) {
        float4 bb = ((const float4*)bias)[cl];
        float o0 = dn * a0 + bb.x;
        float o1 = dn * a1 + bb.y;
        float o2 = dn * a2 + bb.z;
        float o3 = dn * a3 + bb.w;
        if (do_relu) {
            o0 = fmaxf(o0, 0.f); o1 = fmaxf(o1, 0.f);
            o2 = fmaxf(o2, 0.f); o3 = fmaxf(o3, 0.f);
        }
        uint2 ow;
        ow.x = (uint_t)f2bf(o0) | ((uint_t)f2bf(o1) << 16);
        ow.y = (uint_t)f2bf(o2) | ((uint_t)f2bf(o3) << 16);
        ((uint2*)out)[(size_t)node * 32 + cl] = ow;
    }
}

// ---------------- phase-2 weighted reduce (streaming, no atomics) [R21] -----------
// Block bx handles 128 nodes; writes its 128 partials to vpart[bx*128+c] with
// plain stores (each slot written once; visibility via kernel boundary).
__launch_bounds__(512)
__global__ void wreduce2(const ushort_t* __restrict__ h, const float* __restrict__ ow,
                         const float* __restrict__ dinv, float* __restrict__ vpart,
                         int n) {
    __shared__ float s[512];
    int bx = blockIdx.x;
    int tx = threadIdx.x;
    int c = tx & 127;
    int rg = tx >> 7;                    // 0..3
    int base = bx * 128;
    int lim = min(base + 128, n);
    float acc = 0.f;
    for (int r = base + rg; r < lim; r += 4) {
        float dv = dinv[r];
        float cv = dv * (dv + ow[r]);
        acc += cv * bf2f(h[(size_t)r * D + c]);
    }
    s[tx] = acc;
    __syncthreads();
    if (tx < 128)
        vpart[(size_t)bx * 128 + tx] =
            (s[tx] + s[tx + 128]) + (s[tx + 256] + s[tx + 384]);
}

// ---------------- finalize2: reduce vpart + w3 contraction [R21] ------------------
__launch_bounds__(512)
__global__ void finalize2(const float* __restrict__ vpart, int nparts,
                          const float* __restrict__ w3, const float* __restrict__ b3,
                          float* __restrict__ out, float invn) {
    __shared__ float s[512];
    __shared__ float sv[D];
    int tx = threadIdx.x;
    int c = tx & 127;
    int rg = tx >> 7;
    float acc = 0.f;
    for (int p = rg; p < nparts; p += 4)       // independent loads, pipelined
        acc += vpart[(size_t)p * 128 + c];
    s[tx] = acc;
    __syncthreads();
    if (tx < 128)
        sv[tx] = (s[tx] + s[tx + 128]) + (s[tx + 256] + s[tx + 384]);
    __syncthreads();
    if (tx < 128) {
        float f2 = 0.f;
        for (int k = 0; k < D; k++) {
            int p = (k & 15) * 8 + (k >> 4);   // position of original channel k
            f2 += sv[p] * w3[(size_t)k * D + tx];
        }
        out[tx] = f2 * invn + b3[tx];
    }
}

extern "C" void kernel_launch(void* const* d_in, const int* in_sizes, int n_in,
                              void* d_out, int out_size, void* d_ws, size_t ws_size,
                              hipStream_t stream) {
    const float* x   = (const float*)d_in[0];
    const int*   ei  = (const int*)d_in[1];
    const float* w1  = (const float*)d_in[2];
    const float* b1  = (const float*)d_in[3];
    const float* w2  = (const float*)d_in[4];
    const float* b2  = (const float*)d_in[5];
    const float* w3  = (const float*)d_in[6];
    const float* b3  = (const float*)d_in[7];
    float* out = (float*)d_out;

    const int N = in_sizes[0] / D;       // 100000
    const int E = in_sizes[1] / 2;       // 3200000
    const int* src = ei;
    const int* dst = ei + E;
    const int nb = (N + 255) >> 8;       // 391 buckets of 256 nodes
    const int nbin = (E + CH - 1) / CH;  // 391 binning blocks
    const int nw2 = (N + 127) >> 7;      // 782 wreduce2 blocks (128 nodes each)

    // ---- workspace layout ----
    char* p = (char*)d_ws;
    auto alloc = [&](size_t bytes) -> char* {
        char* r = p;
        p += (bytes + 255) & ~(size_t)255;
        return r;
    };
    char*     zbeg     = p;
    int*      curA     = (int*)alloc(512 * 4);
    int*      curB     = (int*)alloc(512 * 4);
    char*     zend     = p;
    float*    ow       = (float*)alloc((size_t)nb * 256 * 4);   // 400 KB
    float*    vpart    = (float*)alloc((size_t)nw2 * 128 * 4);  // 400 KB
    float*    dinv     = (float*)alloc((size_t)N * 4);
    int*      row_beg  = (int*)alloc((size_t)N * 4);
    int*      row_end  = (int*)alloc((size_t)N * 4);
    ushort_t* wp1h     = (ushort_t*)alloc(16384 * 2);
    ushort_t* wp1l     = (ushort_t*)alloc(16384 * 2);
    ushort_t* wp2h     = (ushort_t*)alloc(16384 * 2);
    ushort_t* wp2l     = (ushort_t*)alloc(16384 * 2);
    float*    bp1      = (float*)alloc(D * 4);
    float*    bp2      = (float*)alloc(D * 4);
    uint_t*   binA     = (uint_t*)alloc((size_t)nb * CAP * 4);  // 19.2 MB
    uint_t*   binB     = (uint_t*)alloc((size_t)nb * CAP * 4);  // 19.2 MB
    int*      csr_src  = (int*)alloc((size_t)nb * CAP * 4);     // 19.2 MB
    ushort_t* bufH     = (ushort_t*)alloc((size_t)N * D * 2);   // bf16 agg out
    uint_t*   buf8     = (uint_t*)alloc((size_t)(N + 1) * 32 * 4); // fp8 table + zero row
    (void)ws_size;

    const int gG = (N + 127) / 128;      // MFMA gemm grid (782)

    // zero curA/curB (ow and vpart are fully overwritten each run)
    hipMemsetAsync(zbeg, 0, (size_t)(zend - zbeg), stream);

    // binning + weight pack (one launch; wpack rides in extra blocks)
    k_binpack<<<nbin + 65, 512, 0, stream>>>(src, dst, curA, curB, binA, binB, E, nb,
                                             nbin, w1, w2, wp1h, wp1l, wp2h, wp2l,
                                             b1, b2, bp1, bp2, buf8 + (size_t)N * 32);
    // per-bucket degree/CSR + padding (binA staged in LDS, read once)
    k_csr<<<nb, 1024, 0, stream>>>(binA, curA, dinv, row_beg, row_end, csr_src, N);

    // layer 1 GEMM + ow rider blocks (wreduce phase 1 hides under the GEMM)
    gemm_mfma<1><<<gG + nb, 256, 0, stream>>>(x, wp1h, wp1l, dinv, (uchar_t*)buf8, N,
                                              gG, binB, curB, ow);
    agg8<<<(N + 3) / 4, 256, 0, stream>>>(buf8, csr_src, row_beg, row_end, dinv, bp1,
                                          (uint_t*)bufH, N, 1);
    // layer 2 (A permuted, W2 rows permuted to match) — no riders
    gemm_mfma<0><<<gG, 256, 0, stream>>>(bufH, wp2h, wp2l, dinv, (uchar_t*)buf8, N,
                                         gG, binB, curB, ow);
    agg8<<<(N + 3) / 4, 256, 0, stream>>>(buf8, csr_src, row_beg, row_end, dinv, bp2,
                                          (uint_t*)bufH, N, 1);
    // layer 3 collapsed: streaming weighted reduce -> vpart; tiny finalize
    wreduce2<<<nw2, 512, 0, stream>>>(bufH, ow, dinv, vpart, N);
    finalize2<<<1, 512, 0, stream>>>(vpart, nw2, w3, b3, out, 1.0f / (float)N);
}

// Round 11
// 343.302 us; speedup vs baseline: 1.1549x; 1.1549x over previous
//
#include <hip/hip_runtime.h>

#define D 128
#define BSH 8          // 256 nodes per bucket
#define CAP 12288      // slots per bucket (R17 padding headroom)
#define CH 8192        // edges per k_bin block (512 threads, 391 blocks)
                       // R12 FAILED: per-edge global fp32 atomics ~100us.
                       // R13 WIN: LDS bucket-sort + coalesced copy-out, 428 -> 400us.
                       // R14 WIN: agg8 saddr gathers + prefetch, 400 -> 377us.
                       // R15/R16 FAILED: agg8 grain/depth changes; R14 = local opt.
                       // R17 NEUTRAL: padded CSR; agg8 ~55us structural floor.
                       // R18 WIN: k_bin register edge cache, 377 -> 366us.
                       // R19/R21 REVEALING: wreduce ~61us; then gemm exposed at
                       // ~59us each (MfmaUtil 4%, all pipes idle) — the "unaccounted
                       // 140us" was gemm hiding under agg8's top-5 threshold.
                       // R20 FAILED: serial volatile-accumulate chain (~500cy/iter).
                       // R21 NEUTRAL-REVEALING: wreduce split OK (wreduce2 cheap) but
                       // finalize2 repeated the serial-chain bug (58.7us).
                       // R22: gemm stages Whi+Wlo (64KB) in LDS -> B-frag loads go
                       // from ~200-400cy L2 to ~12cy LDS (the un-hidden latency that
                       // held MfmaUtil at 4%); finalize2/wreduce2 get independent
                       // accumulators (latency/8). NEVER accumulate through a
                       // non-unrolled load-use chain in a small-grid kernel.

typedef unsigned short ushort_t;
typedef unsigned int uint_t;
typedef unsigned char uchar_t;

typedef __attribute__((ext_vector_type(8))) short frag_ab;   // 8 bf16 (4 VGPRs)
typedef __attribute__((ext_vector_type(4))) float frag_cd;   // 4 fp32 acc
typedef __attribute__((ext_vector_type(2))) float float2v;

union frag_u { ushort_t u[8]; frag_ab v; };

// Channel permutation: MFMA C-col c = j*16+l16 stored at position p = (c&15)*8 + (c>>4).
// Inverse: c = (p&7)*16 + (p>>3). Elementwise stages use positions; W2 rows and the
// finalize w3 contraction are permuted to match.

__device__ __forceinline__ float bf2f(ushort_t u) {
    union { uint_t i; float f; } v; v.i = ((uint_t)u) << 16; return v.f;
}
__device__ __forceinline__ ushort_t f2bf(float f) {
    union { float f; uint_t i; } v; v.f = f;
    uint_t u = v.i;
    u += 0x7fffu + ((u >> 16) & 1u);   // round-to-nearest-even
    return (ushort_t)(u >> 16);
}

// fp8 accumulate helpers (agg8)
__device__ __forceinline__ void acc_fp8(uint_t w, float2v& aA, float2v& aB) {
    aA += __builtin_amdgcn_cvt_pk_f32_fp8(w, false);
    aB += __builtin_amdgcn_cvt_pk_f32_fp8(w, true);
}
// gather with explicit 32-bit BYTE offset -> saddr+voffset form [R14]
__device__ __forceinline__ uint_t g8(const uint_t* __restrict__ t8, uint_t byteoff) {
    return *(const uint_t*)((const char*)t8 + byteoff);
}

// ---------------- edge binning + weight pack (merged, disjoint block ranges) ------
__launch_bounds__(512)
__global__ void k_binpack(const int* __restrict__ src, const int* __restrict__ dst,
                          int* __restrict__ curA, int* __restrict__ curB,
                          uint_t* __restrict__ binA, uint_t* __restrict__ binB,
                          int E, int nb, int nbin,
                          const float* __restrict__ W1, const float* __restrict__ W2,
                          ushort_t* __restrict__ h1, ushort_t* __restrict__ l1,
                          ushort_t* __restrict__ h2, ushort_t* __restrict__ l2,
                          const float* __restrict__ b1, const float* __restrict__ b2,
                          float* __restrict__ bp1, float* __restrict__ bp2,
                          uint_t* __restrict__ zrow) {
    int tx = threadIdx.x;

    if (blockIdx.x >= nbin) {                      // ---- weight-pack blocks ----
        int wb = blockIdx.x - nbin;
        if (wb == 64) {                            // bias permute + zero row
            if (tx < 128) {
                int c = (tx & 7) * 16 + (tx >> 3);
                bp1[tx] = b1[c];
                bp2[tx] = b2[c];
            }
            if (tx >= 128 && tx < 160) zrow[tx - 128] = 0;
            return;
        }
        int gid = wb * 512 + tx;                   // 0..32767
        int which = gid >> 14;
        int idx = gid & 16383;
        int k = idx >> 7, n = idx & 127;
        float w = which ? W2[(((k & 7) * 16) + (k >> 3)) * 128 + n] : W1[idx];
        ushort_t h = f2bf(w);
        ushort_t l = f2bf(w - bf2f(h));            // residual -> W effectively fp32
        int c = k >> 5, quad = (k >> 3) & 3, jj = k & 7;
        int j = n >> 4, l16 = n & 15;
        int lane = quad * 16 + l16;
        int dest = ((c * 8 + j) * 64 + lane) * 8 + jj;
        if (which) { h2[dest] = h; l2[dest] = l; }
        else       { h1[dest] = h; l1[dest] = l; }
        return;
    }

    // ---- edge-binning blocks (R13 structure + R18 register cache) ----
    __shared__ int hA[512], hB[512], sc[512], gb[512];
    __shared__ ushort_t sbkt[CH];     // bucket id per local slot
    __shared__ uint_t sent[CH];       // packed entry per local slot (bucket-sorted)
    hA[tx] = 0; hB[tx] = 0;
    __syncthreads();

    int e0 = blockIdx.x * CH;
    int e1 = min(e0 + CH, E);
    int total = e1 - e0;

    int sreg[16], dreg[16];
#pragma unroll
    for (int it = 0; it < 16; ++it) {
        int e = e0 + tx + it * 512;
        if (e < e1) {
            int s = src[e], d = dst[e];
            sreg[it] = s; dreg[it] = d;
            atomicAdd(&hA[d >> BSH], 1);
            atomicAdd(&hB[s >> BSH], 1);
        }
    }
    __syncthreads();

    // ================= side A (dst-keyed) =================
    {
        int v = hA[tx];
        sc[tx] = v;
        __syncthreads();
        for (int d = 1; d < 512; d <<= 1) {
            int t = (tx >= d) ? sc[tx - d] : 0;
            __syncthreads();
            sc[tx] += t;
            __syncthreads();
        }
        sc[tx] -= v;                                   // exclusive scan (local base)
        gb[tx] = v ? atomicAdd(&curA[tx], v) : 0;      // global base (bucket-relative)
        hA[tx] = 0;                                    // reuse as local cursor
        __syncthreads();
#pragma unroll
        for (int it = 0; it < 16; ++it) {
            int e = e0 + tx + it * 512;
            if (e < e1) {
                int s = sreg[it], d = dreg[it];
                int k = d >> BSH;
                int pos = sc[k] + atomicAdd(&hA[k], 1);
                sent[pos] = ((uint_t)s << 8) | (uint_t)(d & 255);
                sbkt[pos] = (ushort_t)k;
            }
        }
        __syncthreads();
        for (int p = tx; p < total; p += 512) {        // run-contiguous, coalesced
            int k = sbkt[p];
            int gp = gb[k] + (p - sc[k]);
            if (gp < CAP) binA[(size_t)k * CAP + gp] = sent[p];
        }
        __syncthreads();
    }

    // ================= side B (src-keyed) =================
    {
        int v = hB[tx];
        sc[tx] = v;
        __syncthreads();
        for (int d = 1; d < 512; d <<= 1) {
            int t = (tx >= d) ? sc[tx - d] : 0;
            __syncthreads();
            sc[tx] += t;
            __syncthreads();
        }
        sc[tx] -= v;
        gb[tx] = v ? atomicAdd(&curB[tx], v) : 0;
        hB[tx] = 0;
        __syncthreads();
#pragma unroll
        for (int it = 0; it < 16; ++it) {
            int e = e0 + tx + it * 512;
            if (e < e1) {
                int s = sreg[it], d = dreg[it];
                int k = s >> BSH;
                int pos = sc[k] + atomicAdd(&hB[k], 1);
                sent[pos] = ((uint_t)d << 8) | (uint_t)(s & 255);
                sbkt[pos] = (ushort_t)k;
            }
        }
        __syncthreads();
        for (int p = tx; p < total; p += 512) {
            int k = sbkt[p];
            int gp = gb[k] + (p - sc[k]);
            if (gp < CAP) binB[(size_t)k * CAP + gp] = sent[p];
        }
    }
}

// ---------------- per-bucket: degree + dinv + row ranges + CSR fill + padding ------
__launch_bounds__(1024)
__global__ void k_csr(const uint_t* __restrict__ binA, const int* __restrict__ curA,
                      float* __restrict__ dinv, int* __restrict__ row_beg,
                      int* __restrict__ row_end, int* __restrict__ csr_src, int N) {
    __shared__ int hist[256];
    __shared__ int scan[256];
    __shared__ uint_t ebuf[CAP];      // 48 KB bucket stage (R19)
    int b = blockIdx.x;
    int tx = threadIdx.x;
    int cnt = min(curA[b], CAP);
    const uint_t* eb = binA + (size_t)b * CAP;

    if (tx < 256) hist[tx] = 0;
    __syncthreads();
    for (int e = tx; e < cnt; e += 1024) {
        uint_t pk = eb[e];
        ebuf[e] = pk;
        atomicAdd(&hist[pk & 255u], 1);
    }
    __syncthreads();
    int v = 0, pd = 0;
    if (tx < 256) {
        v = hist[tx];
        pd = (v + 15) & ~15;             // padded segment length
        scan[tx] = pd;
    }
    __syncthreads();
    for (int dd = 1; dd < 256; dd <<= 1) {
        int t = 0;
        if (tx < 256 && tx >= dd) t = scan[tx - dd];
        __syncthreads();
        if (tx < 256) scan[tx] += t;
        __syncthreads();
    }
    if (tx < 256) {
        int my_excl = scan[tx] - pd;
        int node = b * 256 + tx;
        if (node < N) {
            dinv[node] = rsqrtf((float)(v + 1));        // +1 self-loop (actual deg)
            row_beg[node] = b * CAP + my_excl;
            row_end[node] = b * CAP + my_excl + pd;     // padded length
        }
        for (int i = v; i < pd; i++)
            csr_src[b * CAP + my_excl + i] = N;
        hist[tx] = my_excl;                              // reuse as fill cursor
    }
    __syncthreads();
    for (int e = tx; e < cnt; e += 1024) {
        uint_t pk = ebuf[e];
        int pos = b * CAP + atomicAdd(&hist[pk & 255u], 1);
        csr_src[pos] = (int)(pk >> 8);
    }
}

// ---------------- MFMA GEMM (B tables LDS-staged [R22]) + ow rider blocks ----------
// blocks [0, gemm_blocks): GEMM. Whi+Wlo (64 KB) are cooperatively staged into LDS
//   once per block; B-fragment reads become ds_read_b128 (~12cy vs ~200-400cy L2) —
//   the un-hidden L2 latency was holding MfmaUtil at 4% (R21 counters).
// blocks [gemm_blocks, ...): per-bucket ow computation (reuses the LDS space).
template <int IN_F32>
__launch_bounds__(256)
__global__ void gemm_mfma(const void* __restrict__ Av, const ushort_t* __restrict__ Whi,
                          const ushort_t* __restrict__ Wlo, const float* __restrict__ dinv,
                          uchar_t* __restrict__ C8, int nrows, int gemm_blocks,
                          const uint_t* __restrict__ binB, const int* __restrict__ curB,
                          float* __restrict__ ow) {
    __shared__ ushort_t sW[32768];                 // 64 KB: [0..16K)=hi, [16K..)=lo
    int tx = threadIdx.x;

    if ((int)blockIdx.x >= gemm_blocks) {          // ---- ow rider block ----
        float* owacc = (float*)sW;                 // overlay (1 KB of the 64 KB)
        int b = blockIdx.x - gemm_blocks;
        owacc[tx] = 0.f;
        __syncthreads();
        int cnt = min(curB[b], CAP);
        const uint_t* eb = binB + (size_t)b * CAP;
        for (int e = tx; e < cnt; e += 256) {
            uint_t pk = eb[e];
            atomicAdd(&owacc[pk & 255u], dinv[pk >> 8]);
        }
        __syncthreads();
        ow[b * 256 + tx] = owacc[tx];
        return;
    }

    // stage Whi+Wlo into LDS (coalesced, 8 iters x 2 x 16B per thread)
    {
        uint4* dW = (uint4*)sW;
        const uint4* sH = (const uint4*)Whi;
        const uint4* sL = (const uint4*)Wlo;
        for (int i = tx; i < 2048; i += 256) {
            dW[i] = sH[i];
            dW[i + 2048] = sL[i];
        }
    }
    __syncthreads();

    int wave = tx >> 6;
    int lane = tx & 63;
    int quad = lane >> 4, l16 = lane & 15;
    int base = blockIdx.x * 128 + wave * 32;

    frag_cd acc[2][8];
#pragma unroll
    for (int rt = 0; rt < 2; rt++)
#pragma unroll
        for (int j = 0; j < 8; j++) acc[rt][j] = (frag_cd)0.f;

    const ushort_t* Ab = (const ushort_t*)Av;
    const float* Af = (const float*)Av;

#pragma unroll
    for (int c = 0; c < 4; c++) {
        frag_ab afrag[2];
        int koff = c * 32 + quad * 8;
#pragma unroll
        for (int rt = 0; rt < 2; rt++) {
            int row = min(base + rt * 16 + l16, nrows - 1);
            if (IN_F32) {
                const float* ap = Af + (size_t)row * D + koff;
                float4 a0 = *(const float4*)ap;
                float4 a1 = *(const float4*)(ap + 4);
                frag_u fu;
                fu.u[0] = f2bf(a0.x); fu.u[1] = f2bf(a0.y);
                fu.u[2] = f2bf(a0.z); fu.u[3] = f2bf(a0.w);
                fu.u[4] = f2bf(a1.x); fu.u[5] = f2bf(a1.y);
                fu.u[6] = f2bf(a1.z); fu.u[7] = f2bf(a1.w);
                afrag[rt] = fu.v;
            } else {
                afrag[rt] = *(const frag_ab*)(Ab + (size_t)row * D + koff);
            }
        }
#pragma unroll
        for (int j = 0; j < 8; j++) {
            int boff = ((c * 8 + j) * 64 + lane) * 8;
            frag_ab bh = *(const frag_ab*)(sW + boff);
            frag_ab bl = *(const frag_ab*)(sW + 16384 + boff);
#pragma unroll
            for (int rt = 0; rt < 2; rt++) {
                acc[rt][j] = __builtin_amdgcn_mfma_f32_16x16x32_bf16(afrag[rt], bh,
                                                                     acc[rt][j], 0, 0, 0);
                acc[rt][j] = __builtin_amdgcn_mfma_f32_16x16x32_bf16(afrag[rt], bl,
                                                                     acc[rt][j], 0, 0, 0);
            }
        }
    }

#pragma unroll
    for (int rt = 0; rt < 2; rt++) {
        int rbase = base + rt * 16 + quad * 4;
#pragma unroll
        for (int reg = 0; reg < 4; reg++) {
            int row = rbase + reg;
            if (row < nrows) {
                float dv = dinv[row];
                uint_t d0 = (uint_t)__builtin_amdgcn_cvt_pk_fp8_f32(
                    acc[rt][0][reg] * dv, acc[rt][1][reg] * dv, 0, false);
                d0 = (uint_t)__builtin_amdgcn_cvt_pk_fp8_f32(
                    acc[rt][2][reg] * dv, acc[rt][3][reg] * dv, (int)d0, true);
                uint_t d1 = (uint_t)__builtin_amdgcn_cvt_pk_fp8_f32(
                    acc[rt][4][reg] * dv, acc[rt][5][reg] * dv, 0, false);
                d1 = (uint_t)__builtin_amdgcn_cvt_pk_fp8_f32(
                    acc[rt][6][reg] * dv, acc[rt][7][reg] * dv, (int)d1, true);
                uint2 o; o.x = d0; o.y = d1;
                *(uint2*)(C8 + (size_t)row * D + l16 * 8) = o;
            }
        }
    }
}

// ---------------- aggregation (pre-scaled fp8 gather, pure sum, bf16 out) ----------
// R14 shape + R17 padded tail-free loop. ~55us structural floor — frozen.
__launch_bounds__(256)
__global__ void agg8(const uint_t* __restrict__ t8, const int* __restrict__ csr_src,
                     const int* __restrict__ row_beg, const int* __restrict__ row_end,
                     const float* __restrict__ dinv, const float* __restrict__ bias,
                     uint_t* __restrict__ out, int n, int do_relu) {
    int node = blockIdx.x * 4 + (threadIdx.x >> 6);
    if (node >= n) return;
    int lane = threadIdx.x & 63;
    int eh = lane >> 5;
    uint_t cl = (uint_t)(lane & 31);
    uint_t cl4 = cl * 4u;

    int beg = row_beg[node];
    int cnt = row_end[node] - beg;     // padded, multiple of 16
    float dn = dinv[node];

    float2v accA = {0.f, 0.f}, accB = {0.f, 0.f};

    if (eh == 0) {   // self term: table already holds dinv[n]*t[n]
        uint_t w = g8(t8, (uint_t)node * 128u + cl4);
        accA = __builtin_amdgcn_cvt_pk_f32_fp8(w, false);
        accB = __builtin_amdgcn_cvt_pk_f32_fp8(w, true);
    }

    int half = cnt >> 1;               // multiple of 8, same for both halves
    int e     = beg + (eh ? half : 0);
    int nfull = half >> 3;             // uniform across the wave

    uint4 sa, sb;
    if (nfull > 0) {
        __builtin_memcpy(&sa, csr_src + e, 16);        // 4B-aligned 16B loads
        __builtin_memcpy(&sb, csr_src + e + 4, 16);
    }
    for (int it = 0; it < nfull; ++it) {
        uint4 ca = sa, cb = sb;
        e += 8;
        if (it + 1 < nfull) {               // prefetch next batch's indices early
            __builtin_memcpy(&sa, csr_src + e, 16);
            __builtin_memcpy(&sb, csr_src + e + 4, 16);
        }
        uint_t w0 = g8(t8, ca.x * 128u + cl4);
        uint_t w1 = g8(t8, ca.y * 128u + cl4);
        uint_t w2 = g8(t8, ca.z * 128u + cl4);
        uint_t w3 = g8(t8, ca.w * 128u + cl4);
        uint_t w4 = g8(t8, cb.x * 128u + cl4);
        uint_t w5 = g8(t8, cb.y * 128u + cl4);
        uint_t w6 = g8(t8, cb.z * 128u + cl4);
        uint_t w7 = g8(t8, cb.w * 128u + cl4);
        acc_fp8(w0, accA, accB);
        acc_fp8(w1, accA, accB);
        acc_fp8(w2, accA, accB);
        acc_fp8(w3, accA, accB);
        acc_fp8(w4, accA, accB);
        acc_fp8(w5, accA, accB);
        acc_fp8(w6, accA, accB);
        acc_fp8(w7, accA, accB);
    }

    float a0 = accA.x, a1 = accA.y, a2 = accB.x, a3 = accB.y;
    a0 += __shfl(a0, lane ^ 32, 64);
    a1 += __shfl(a1, lane ^ 32, 64);
    a2 += __shfl(a2, lane ^ 32, 64);
    a3 += __shfl(a3, lane ^ 32, 64);

    if (eh == 0) {
        float4 bb = ((const float4*)bias)[cl];
        float o0 = dn * a0 + bb.x;
        float o1 = dn * a1 + bb.y;
        float o2 = dn * a2 + bb.z;
        float o3 = dn * a3 + bb.w;
        if (do_relu) {
            o0 = fmaxf(o0, 0.f); o1 = fmaxf(o1, 0.f);
            o2 = fmaxf(o2, 0.f); o3 = fmaxf(o3, 0.f);
        }
        uint2 ow;
        ow.x = (uint_t)f2bf(o0) | ((uint_t)f2bf(o1) << 16);
        ow.y = (uint_t)f2bf(o2) | ((uint_t)f2bf(o3) << 16);
        ((uint2*)out)[(size_t)node * 32 + cl] = ow;
    }
}

// ---------------- phase-2 weighted reduce (streaming, no atomics) [R21] -----------
// R22: 2 independent accumulators (row pairs r, r+4) to pipeline the h loads.
__launch_bounds__(512)
__global__ void wreduce2(const ushort_t* __restrict__ h, const float* __restrict__ ow,
                         const float* __restrict__ dinv, float* __restrict__ vpart,
                         int n) {
    __shared__ float s[512];
    int bx = blockIdx.x;
    int tx = threadIdx.x;
    int c = tx & 127;
    int rg = tx >> 7;                    // 0..3
    int base = bx * 128;
    int lim = min(base + 128, n);
    float acc0 = 0.f, acc1 = 0.f;
    int r = base + rg;
    for (; r + 4 < lim; r += 8) {
        float dv0 = dinv[r];
        float cv0 = dv0 * (dv0 + ow[r]);
        acc0 += cv0 * bf2f(h[(size_t)r * D + c]);
        int r1 = r + 4;
        float dv1 = dinv[r1];
        float cv1 = dv1 * (dv1 + ow[r1]);
        acc1 += cv1 * bf2f(h[(size_t)r1 * D + c]);
    }
    if (r < lim) {
        float dv0 = dinv[r];
        float cv0 = dv0 * (dv0 + ow[r]);
        acc0 += cv0 * bf2f(h[(size_t)r * D + c]);
    }
    s[tx] = acc0 + acc1;
    __syncthreads();
    if (tx < 128)
        vpart[(size_t)bx * 128 + tx] =
            (s[tx] + s[tx + 128]) + (s[tx + 256] + s[tx + 384]);
}

// ---------------- finalize2: reduce vpart + w3 contraction [R22 ILP fix] -----------
// R21's version was a serial load-use chain (195 + 128 iterations x ~500cy = 58.7us
// measured). 8 independent accumulators in both loops -> latency/8.
__launch_bounds__(512)
__global__ void finalize2(const float* __restrict__ vpart, int nparts,
                          const float* __restrict__ w3, const float* __restrict__ b3,
                          float* __restrict__ out, float invn) {
    __shared__ float s[512];
    __shared__ float sv[D];
    int tx = threadIdx.x;
    int c = tx & 127;
    int rg = tx >> 7;
    float a0 = 0.f, a1 = 0.f, a2 = 0.f, a3 = 0.f;
    float a4 = 0.f, a5 = 0.f, a6 = 0.f, a7 = 0.f;
    int p = rg;
    for (; p + 28 < nparts; p += 32) {       // 8 independent loads in flight
        a0 += vpart[(size_t)(p)      * 128 + c];
        a1 += vpart[(size_t)(p +  4) * 128 + c];
        a2 += vpart[(size_t)(p +  8) * 128 + c];
        a3 += vpart[(size_t)(p + 12) * 128 + c];
        a4 += vpart[(size_t)(p + 16) * 128 + c];
        a5 += vpart[(size_t)(p + 20) * 128 + c];
        a6 += vpart[(size_t)(p + 24) * 128 + c];
        a7 += vpart[(size_t)(p + 28) * 128 + c];
    }
    for (; p < nparts; p += 4) a0 += vpart[(size_t)p * 128 + c];
    s[tx] = ((a0 + a1) + (a2 + a3)) + ((a4 + a5) + (a6 + a7));
    __syncthreads();
    if (tx < 128)
        sv[tx] = (s[tx] + s[tx + 128]) + (s[tx + 256] + s[tx + 384]);
    __syncthreads();
    if (tx < 128) {
        float f0 = 0.f, f1 = 0.f, f2 = 0.f, f3 = 0.f;
        float f4 = 0.f, f5 = 0.f, f6 = 0.f, f7 = 0.f;
        for (int k0 = 0; k0 < D; k0 += 8) {  // 8 independent w3 loads in flight
            f0 += sv[((k0    ) & 15) * 8 + ((k0    ) >> 4)] * w3[(size_t)(k0    ) * D + tx];
            f1 += sv[((k0 + 1) & 15) * 8 + ((k0 + 1) >> 4)] * w3[(size_t)(k0 + 1) * D + tx];
            f2 += sv[((k0 + 2) & 15) * 8 + ((k0 + 2) >> 4)] * w3[(size_t)(k0 + 2) * D + tx];
            f3 += sv[((k0 + 3) & 15) * 8 + ((k0 + 3) >> 4)] * w3[(size_t)(k0 + 3) * D + tx];
            f4 += sv[((k0 + 4) & 15) * 8 + ((k0 + 4) >> 4)] * w3[(size_t)(k0 + 4) * D + tx];
            f5 += sv[((k0 + 5) & 15) * 8 + ((k0 + 5) >> 4)] * w3[(size_t)(k0 + 5) * D + tx];
            f6 += sv[((k0 + 6) & 15) * 8 + ((k0 + 6) >> 4)] * w3[(size_t)(k0 + 6) * D + tx];
            f7 += sv[((k0 + 7) & 15) * 8 + ((k0 + 7) >> 4)] * w3[(size_t)(k0 + 7) * D + tx];
        }
        float f = ((f0 + f1) + (f2 + f3)) + ((f4 + f5) + (f6 + f7));
        out[tx] = f * invn + b3[tx];
    }
}

extern "C" void kernel_launch(void* const* d_in, const int* in_sizes, int n_in,
                              void* d_out, int out_size, void* d_ws, size_t ws_size,
                              hipStream_t stream) {
    const float* x   = (const float*)d_in[0];
    const int*   ei  = (const int*)d_in[1];
    const float* w1  = (const float*)d_in[2];
    const float* b1  = (const float*)d_in[3];
    const float* w2  = (const float*)d_in[4];
    const float* b2  = (const float*)d_in[5];
    const float* w3  = (const float*)d_in[6];
    const float* b3  = (const float*)d_in[7];
    float* out = (float*)d_out;

    const int N = in_sizes[0] / D;       // 100000
    const int E = in_sizes[1] / 2;       // 3200000
    const int* src = ei;
    const int* dst = ei + E;
    const int nb = (N + 255) >> 8;       // 391 buckets of 256 nodes
    const int nbin = (E + CH - 1) / CH;  // 391 binning blocks
    const int nw2 = (N + 127) >> 7;      // 782 wreduce2 blocks (128 nodes each)

    // ---- workspace layout ----
    char* p = (char*)d_ws;
    auto alloc = [&](size_t bytes) -> char* {
        char* r = p;
        p += (bytes + 255) & ~(size_t)255;
        return r;
    };
    char*     zbeg     = p;
    int*      curA     = (int*)alloc(512 * 4);
    int*      curB     = (int*)alloc(512 * 4);
    char*     zend     = p;
    float*    ow       = (float*)alloc((size_t)nb * 256 * 4);   // 400 KB
    float*    vpart    = (float*)alloc((size_t)nw2 * 128 * 4);  // 400 KB
    float*    dinv     = (float*)alloc((size_t)N * 4);
    int*      row_beg  = (int*)alloc((size_t)N * 4);
    int*      row_end  = (int*)alloc((size_t)N * 4);
    ushort_t* wp1h     = (ushort_t*)alloc(16384 * 2);
    ushort_t* wp1l     = (ushort_t*)alloc(16384 * 2);
    ushort_t* wp2h     = (ushort_t*)alloc(16384 * 2);
    ushort_t* wp2l     = (ushort_t*)alloc(16384 * 2);
    float*    bp1      = (float*)alloc(D * 4);
    float*    bp2      = (float*)alloc(D * 4);
    uint_t*   binA     = (uint_t*)alloc((size_t)nb * CAP * 4);  // 19.2 MB
    uint_t*   binB     = (uint_t*)alloc((size_t)nb * CAP * 4);  // 19.2 MB
    int*      csr_src  = (int*)alloc((size_t)nb * CAP * 4);     // 19.2 MB
    ushort_t* bufH     = (ushort_t*)alloc((size_t)N * D * 2);   // bf16 agg out
    uint_t*   buf8     = (uint_t*)alloc((size_t)(N + 1) * 32 * 4); // fp8 table + zero row
    (void)ws_size;

    const int gG = (N + 127) / 128;      // MFMA gemm grid (782)

    // zero curA/curB (ow and vpart are fully overwritten each run)
    hipMemsetAsync(zbeg, 0, (size_t)(zend - zbeg), stream);

    // binning + weight pack (one launch; wpack rides in extra blocks)
    k_binpack<<<nbin + 65, 512, 0, stream>>>(src, dst, curA, curB, binA, binB, E, nb,
                                             nbin, w1, w2, wp1h, wp1l, wp2h, wp2l,
                                             b1, b2, bp1, bp2, buf8 + (size_t)N * 32);
    // per-bucket degree/CSR + padding (binA staged in LDS, read once)
    k_csr<<<nb, 1024, 0, stream>>>(binA, curA, dinv, row_beg, row_end, csr_src, N);

    // layer 1 GEMM (B LDS-staged) + ow rider blocks (hide under the GEMM)
    gemm_mfma<1><<<gG + nb, 256, 0, stream>>>(x, wp1h, wp1l, dinv, (uchar_t*)buf8, N,
                                              gG, binB, curB, ow);
    agg8<<<(N + 3) / 4, 256, 0, stream>>>(buf8, csr_src, row_beg, row_end, dinv, bp1,
                                          (uint_t*)bufH, N, 1);
    // layer 2 (A permuted, W2 rows permuted to match) — no riders
    gemm_mfma<0><<<gG, 256, 0, stream>>>(bufH, wp2h, wp2l, dinv, (uchar_t*)buf8, N,
                                         gG, binB, curB, ow);
    agg8<<<(N + 3) / 4, 256, 0, stream>>>(buf8, csr_src, row_beg, row_end, dinv, bp2,
                                          (uint_t*)bufH, N, 1);
    // layer 3 collapsed: streaming weighted reduce -> vpart; tiny finalize
    wreduce2<<<nw2, 512, 0, stream>>>(bufH, ow, dinv, vpart, N);
    finalize2<<<1, 512, 0, stream>>>(vpart, nw2, w3, b3, out, 1.0f / (float)N);
}